// Round 9
// baseline (771.449 us; speedup 1.0000x reference)
//
#include <hip/hip_runtime.h>

// GGNN layer, B=64, N=512, D=512, steps=2. Numerics = rounds 6-8 exactly
// (fp16 + power-of-2 scaling, split passes on r/hc path; absmax 131072).
// r9: L3-residency attack. M-chunked x2 (working set/chunk ~180MB < 256MB L3),
// tile 128x256 (256 blocks/chunk-dispatch), ring-3 LDS (144KB) staged 2 tiles
// ahead, one counted vmcnt(6)/tile, two-barrier phases (m201), XCD affinity:
// row-block -> XCD invariant across dispatches (rb = swz>>1, xcd = swz>>5).

#define LD 512
#define CFENCE asm volatile("" ::: "memory")

typedef unsigned short u16;
typedef _Float16 f16;
typedef f16 f16x8 __attribute__((ext_vector_type(8)));
typedef float f32x4 __attribute__((ext_vector_type(4)));

__device__ __forceinline__ u16 f2h(float f) { f16 h = (f16)f; return *(u16*)&h; }
__device__ __forceinline__ float h2f(u16 b) { f16 h = *(f16*)&b; return (float)h; }

__device__ __forceinline__ void gload16(const void* g, void* l) {
  __builtin_amdgcn_global_load_lds(
      (const __attribute__((address_space(1))) void*)g,
      (__attribute__((address_space(3))) void*)l, 16, 0, 0);
}

// ---------------- f32 -> f16 single ----------------
__global__ void cvt_f16(const float* __restrict__ in, u16* __restrict__ out, int n4) {
  int i = blockIdx.x * blockDim.x + threadIdx.x;
  if (i >= n4) return;
  float4 v = reinterpret_cast<const float4*>(in)[i];
  ushort4 o;
  o.x = f2h(v.x); o.y = f2h(v.y); o.z = f2h(v.z); o.w = f2h(v.w);
  reinterpret_cast<ushort4*>(out)[i] = o;
}

// ---------------- f32 -> f16 hi/lo split ----------------
__global__ void cvt2h(const float* __restrict__ in, u16* __restrict__ ohi,
                      u16* __restrict__ olo, int n4) {
  int i = blockIdx.x * blockDim.x + threadIdx.x;
  if (i >= n4) return;
  float4 v = reinterpret_cast<const float4*>(in)[i];
  ushort4 h, l;
  h.x = f2h(v.x); l.x = f2h(v.x - h2f(h.x));
  h.y = f2h(v.y); l.y = f2h(v.y - h2f(h.y));
  h.z = f2h(v.z); l.z = f2h(v.z - h2f(h.z));
  h.w = f2h(v.w); l.w = f2h(v.w - h2f(h.w));
  reinterpret_cast<ushort4*>(ohi)[i] = h;
  reinterpret_cast<ushort4*>(olo)[i] = l;
}

// ------- weight f32 [K][N] -> f16 single (scaled), transposed [N][K] -------
__global__ void wconv1(const float* __restrict__ in, u16* __restrict__ out, float scale) {
  __shared__ float sm[32][33];
  int tx = threadIdx.x & 31, ty = threadIdx.x >> 5;
  int k0 = blockIdx.y * 32, n0 = blockIdx.x * 32;
#pragma unroll
  for (int i = 0; i < 32; i += 8)
    sm[ty + i][tx] = in[(size_t)(k0 + ty + i) * LD + n0 + tx];
  __syncthreads();
#pragma unroll
  for (int i = 0; i < 32; i += 8)
    out[(size_t)(n0 + ty + i) * LD + k0 + tx] = f2h(sm[tx][ty + i] * scale);
}

// ------- weight f32 [K][N] -> f16 hi/lo (scaled), transposed [N][K] -------
__global__ void wconv2h(const float* __restrict__ in, u16* __restrict__ ohi,
                        u16* __restrict__ olo, float scale) {
  __shared__ float sm[32][33];
  int tx = threadIdx.x & 31, ty = threadIdx.x >> 5;
  int k0 = blockIdx.y * 32, n0 = blockIdx.x * 32;
#pragma unroll
  for (int i = 0; i < 32; i += 8)
    sm[ty + i][tx] = in[(size_t)(k0 + ty + i) * LD + n0 + tx];
  __syncthreads();
#pragma unroll
  for (int i = 0; i < 32; i += 8) {
    float v = sm[tx][ty + i] * scale;
    u16 hi = f2h(v);
    size_t o = (size_t)(n0 + ty + i) * LD + k0 + tx;
    ohi[o] = hi;
    olo[o] = f2h(v - h2f(hi));
  }
}

// -------- u16 transpose per batch: [B][N][D] -> [B][D][N] --------
__global__ void transp16(const u16* __restrict__ in, u16* __restrict__ out) {
  __shared__ u16 sm[64][65];
  int b = blockIdx.z;
  int n0 = blockIdx.y * 64, d0 = blockIdx.x * 64;
  int lane = threadIdx.x & 63, grp = threadIdx.x >> 6;
  const u16* src = in + ((size_t)b * LD + n0) * LD + d0;
#pragma unroll
  for (int i = grp; i < 64; i += 4)
    sm[i][lane] = src[(size_t)i * LD + lane];
  __syncthreads();
  u16* dst = out + ((size_t)b * LD + d0) * LD + n0;
#pragma unroll
  for (int i = grp; i < 64; i += 4)
    dst[(size_t)i * LD + lane] = sm[lane][i];
}

// ---------------- fp16 MFMA GEMM, 128x256 tile, ring-3, 2-barrier phases ----------------
struct Desc {
  const u16* A[6];
  const u16* B[6];
  long bsA, bsB;
  int rowOff;   // flat modes: row offset of this chunk
  int bzOff;    // MODE 1: batch offset of this chunk
  const float* bias1;
  const float* mask;
  const float* hf32;
  const u16* z16;
  float* outf;
  u16* o16;
  u16* o16b;
};

#define BUFU 24576  // u16 per ring buffer: A 128x64 (8192) + B 256x64 (16384)

template <int MODE, int NA>
__global__ __launch_bounds__(512, 2) void gemm9(Desc d) {
  constexpr int NT = NA * 8;  // K-tiles of 64

  __shared__ __align__(16) u16 lds[3 * BUFU];  // 144 KiB ring

  const int t = threadIdx.x;
  const int lane = t & 63;
  const int wid = t >> 6;
  const int wr = wid >> 2, wc = wid & 3;  // 2x4 waves, each 64x64 of C

  // swizzle: rb = swz>>1 -> xcd = swz>>5, invariant across all dispatches
  const int id = (int)blockIdx.x;
  const int swz = (id & 7) * 32 + (id >> 3);
  const int bx = swz & 1;
  size_t baseA, baseB;
  int rowBase0;
  if (MODE == 1) {
    const int by2 = (swz >> 1) & 3;
    const size_t bz = (size_t)(swz >> 3) + d.bzOff;
    baseA = bz * d.bsA + (size_t)by2 * 128 * LD;
    baseB = bz * d.bsB + (size_t)bx * 256 * LD;
    rowBase0 = (int)bz * 512 + by2 * 128;
  } else {
    const int by = swz >> 1;
    baseA = (size_t)(d.rowOff + by * 128) * LD;
    baseB = (size_t)bx * 256 * LD;
    rowBase0 = d.rowOff + by * 128;
  }

  // staging map: thread t handles 16B chunks c = t + 512k; row = sr+64k,
  // source col pre-swizzled (rule 21), LDS dest linear.
  const int sr = t >> 3;
  const int sc = ((t & 7) ^ (sr & 7)) * 8;

  // ds-read offsets (u16): frag row r -> kslot chunk (ks*4+lk) ^ (r&7)
  const int lsw = lane & 7;
  const int lk = lane >> 4;
  const int rowA = wr * 64 + (lane & 15);
  const int rowB = wc * 64 + (lane & 15);
  int aofs[2], bofs[2];
#pragma unroll
  for (int ks = 0; ks < 2; ++ks) {
    aofs[ks] = rowA * 64 + (((ks * 4 + lk) ^ lsw) * 8);
    bofs[ks] = 8192 + rowB * 64 + (((ks * 4 + lk) ^ lsw) * 8);
  }

  f32x4 acc[4][4] = {};

  // stage 3 of the 6 chunks for tile -> buffer LS (ph0: B k=0..2; ph1: B k=3 + A k=0,1)
  auto stage3 = [&](const u16* ApS, const u16* BpS, int kbS, u16* LS, int ph) {
    if (ph == 0) {
#pragma unroll
      for (int k = 0; k < 3; ++k)
        gload16(BpS + (size_t)(sr + 64 * k) * LD + kbS + sc,
                LS + 8192 + (t + 512 * k) * 8);
    } else {
      gload16(BpS + (size_t)(sr + 192) * LD + kbS + sc, LS + 8192 + (t + 1536) * 8);
#pragma unroll
      for (int k = 0; k < 2; ++k)
        gload16(ApS + (size_t)(sr + 64 * k) * LD + kbS + sc, LS + (t + 512 * k) * 8);
    }
  };

  // prologue: stage tiles 0,1 of pass 0
  {
    const u16* Ap0 = d.A[0] + baseA;
    const u16* Bp0 = d.B[0] + baseB;
    stage3(Ap0, Bp0, 0, lds, 0);
    stage3(Ap0, Bp0, 0, lds, 1);
    stage3(Ap0, Bp0, 64, lds + BUFU, 0);
    stage3(Ap0, Bp0, 64, lds + BUFU, 1);
  }
  asm volatile("s_waitcnt vmcnt(6)" ::: "memory");
  __builtin_amdgcn_s_barrier();

  int bR = 0;
#pragma unroll
  for (int s = 0; s < NA; ++s) {
    const u16* Ap = d.A[s] + baseA;
    const u16* Bp = d.B[s] + baseB;
    const u16* ApN = d.A[s + 1 < NA ? s + 1 : s] + baseA;  // compile-time index
    const u16* BpN = d.B[s + 1 < NA ? s + 1 : s] + baseB;
    for (int kt = 0; kt < 8; ++kt) {
      const int tt = s * 8 + kt;
      const u16* L = lds + bR * BUFU;
      u16* LS = lds + (bR >= 1 ? bR - 1 : 2) * BUFU;  // (tt+2)%3
      const bool st = (tt + 2) < NT;
      const u16* ApS = kt < 6 ? Ap : ApN;
      const u16* BpS = kt < 6 ? Bp : BpN;
      const int kbS = ((kt + 2) & 7) * 64;

      // ---- phase 0: read B(all) + A i=0,1 ; stage 3 ; MFMA i=0,1 ----
      f16x8 bfr[4][2], af0[2][2];
#pragma unroll
      for (int j = 0; j < 4; ++j)
#pragma unroll
        for (int ks = 0; ks < 2; ++ks)
          bfr[j][ks] = *(const f16x8*)&L[bofs[ks] + j * 1024];
#pragma unroll
      for (int di = 0; di < 2; ++di)
#pragma unroll
        for (int ks = 0; ks < 2; ++ks)
          af0[di][ks] = *(const f16x8*)&L[aofs[ks] + di * 1024];
      if (st) stage3(ApS, BpS, kbS, LS, 0);
      CFENCE;
      __builtin_amdgcn_s_barrier();
      asm volatile("s_waitcnt lgkmcnt(0)" ::: "memory");
      __builtin_amdgcn_sched_barrier(0);
      __builtin_amdgcn_s_setprio(1);
#pragma unroll
      for (int di = 0; di < 2; ++di)
#pragma unroll
        for (int j = 0; j < 4; ++j) {
          acc[di][j] = __builtin_amdgcn_mfma_f32_16x16x32_f16(
              af0[di][0], bfr[j][0], acc[di][j], 0, 0, 0);
          acc[di][j] = __builtin_amdgcn_mfma_f32_16x16x32_f16(
              af0[di][1], bfr[j][1], acc[di][j], 0, 0, 0);
        }
      __builtin_amdgcn_s_setprio(0);
      CFENCE;
      __builtin_amdgcn_s_barrier();

      // ---- phase 1: read A i=2,3 ; stage 3 ; MFMA i=2,3 ; vmcnt ----
      f16x8 af1[2][2];
#pragma unroll
      for (int di = 0; di < 2; ++di)
#pragma unroll
        for (int ks = 0; ks < 2; ++ks)
          af1[di][ks] = *(const f16x8*)&L[aofs[ks] + (2 + di) * 1024];
      if (st) stage3(ApS, BpS, kbS, LS, 1);
      CFENCE;
      __builtin_amdgcn_s_barrier();
      asm volatile("s_waitcnt lgkmcnt(0)" ::: "memory");
      __builtin_amdgcn_sched_barrier(0);
      __builtin_amdgcn_s_setprio(1);
#pragma unroll
      for (int di = 0; di < 2; ++di)
#pragma unroll
        for (int j = 0; j < 4; ++j) {
          acc[2 + di][j] = __builtin_amdgcn_mfma_f32_16x16x32_f16(
              af1[di][0], bfr[j][0], acc[2 + di][j], 0, 0, 0);
          acc[2 + di][j] = __builtin_amdgcn_mfma_f32_16x16x32_f16(
              af1[di][1], bfr[j][1], acc[2 + di][j], 0, 0, 0);
        }
      __builtin_amdgcn_s_setprio(0);
      if (st) {
        asm volatile("s_waitcnt vmcnt(6)" ::: "memory");  // drains tile tt+1's loads
      } else {
        asm volatile("s_waitcnt vmcnt(0)" ::: "memory");
      }
      CFENCE;
      __builtin_amdgcn_s_barrier();
      bR = bR == 2 ? 0 : bR + 1;
    }
  }

  // epilogue: C/D layout col=lane&15, row=(lane>>4)*4+reg [m89-verified]
  const float S4 = 0.0625f;          // 2^-4
  const float S12 = 2.44140625e-4f;  // 2^-12
  const int rowBase = rowBase0 + wr * 64 + (lane >> 4) * 4;
  const int colBase = bx * 256 + wc * 64 + (lane & 15);
#pragma unroll
  for (int i = 0; i < 4; ++i) {
#pragma unroll
    for (int j = 0; j < 4; ++j) {
      const int col = colBase + j * 16;
      const float bv = d.bias1[col];
#pragma unroll
      for (int r = 0; r < 4; ++r) {
        const int row = rowBase + i * 16 + r;
        const size_t idx = (size_t)row * LD + col;
        const float a = acc[i][j][r];
        if (MODE == 0) {
          float v = fmaxf(a + bv, 0.0f) * d.mask[row];
          d.outf[idx] = v;
          d.o16[idx] = f2h(v * S4);
        } else if (MODE == 1) {
          float v = a + bv * S4;
          u16 hi = f2h(v);
          d.o16[idx] = hi;
          d.o16b[idx] = f2h(v - h2f(hi));
        } else if (MODE == 2) {
          float v = fmaxf(a + bv, 0.0f);
          d.o16[idx] = f2h(v * S4);
        } else if (MODE == 3) {
          float v = fmaxf(a + bv, 0.0f) * d.hf32[idx];
          u16 hi = f2h(v * S12);
          d.o16[idx] = hi;
          float rec = h2f(hi) * 4096.0f;
          d.o16b[idx] = f2h((v - rec) * S12);
        } else {
          float hc = tanhf(a + bv) * d.mask[row];
          float z = 16.0f * h2f(d.z16[idx]);
          float h = d.hf32[idx];
          float hn = (1.0f - z) * h + z * hc;
          d.outf[idx] = hn;
          d.o16[idx] = f2h(hn * S4);
        }
      }
    }
  }
}

extern "C" void kernel_launch(void* const* d_in, const int* in_sizes, int n_in,
                              void* d_out, int out_size, void* d_ws, size_t ws_size,
                              hipStream_t stream) {
  const float* x    = (const float*)d_in[0];
  const float* adj  = (const float*)d_in[1];
  const float* mask = (const float*)d_in[2];
  const float* Wenc = (const float*)d_in[3];
  const float* benc = (const float*)d_in[4];
  const float* Wz   = (const float*)d_in[5];
  const float* Uz   = (const float*)d_in[6];
  const float* bz_  = (const float*)d_in[7];
  const float* Wr   = (const float*)d_in[8];
  const float* Ur   = (const float*)d_in[9];
  const float* br_  = (const float*)d_in[10];
  const float* Wh   = (const float*)d_in[11];
  const float* Uh   = (const float*)d_in[12];
  const float* bh_  = (const float*)d_in[13];
  const float* ba_  = (const float*)d_in[14];

  float* hf = (float*)d_out;  // h in f32 across steps (64 MiB)

  const size_t SZ  = (size_t)64 * 512 * 512 * sizeof(u16);  // 32 MiB
  const size_t WSZ = (size_t)LD * LD * sizeof(u16);         // 0.5 MiB
  const size_t NEED = 7 * SZ + 11 * WSZ;                    // 229.5 MiB
  if (ws_size < NEED) return;

  char* p = (char*)d_ws;
  u16* adj16 = (u16*)p; p += SZ;
  u16* h16   = (u16*)p; p += SZ;   // h * 2^-4
  u16* a_hi  = (u16*)p; p += SZ;   // a*2^-4 hi ; aliased: x_hi before encoder
  u16* a_lo  = (u16*)p; p += SZ;   // a*2^-4 lo ; aliased: x_lo before encoder
  u16* zht   = (u16*)p; p += SZ;   // h^T*2^-4 (transp..A), then z*2^-4 (Z..GRU)
  u16* rh_hi = (u16*)p; p += SZ;   // rh*2^-12 hi
  u16* rh_lo = (u16*)p; p += SZ;   // rh*2^-12 lo
  u16* w     = (u16*)p;
  u16* We_h = w + 0 * LD * LD;  u16* We_l = w + 1 * LD * LD;   // x1
  u16* Wz1  = w + 2 * LD * LD;                                  // x16
  u16* Uz1  = w + 3 * LD * LD;                                  // x16
  u16* Wr_h = w + 4 * LD * LD;  u16* Wr_l = w + 5 * LD * LD;   // x16
  u16* Ur1  = w + 6 * LD * LD;                                  // x16
  u16* Wh_h = w + 7 * LD * LD;  u16* Wh_l = w + 8 * LD * LD;   // x16
  u16* Uh_h = w + 9 * LD * LD;  u16* Uh_l = w + 10 * LD * LD;  // x4096
  u16* x_hi = a_hi;
  u16* x_lo = a_lo;

  const int NELT = 64 * 512 * 512;
  cvt2h<<<NELT / 4 / 256, 256, 0, stream>>>(x, x_hi, x_lo, NELT / 4);
  cvt_f16<<<NELT / 4 / 256, 256, 0, stream>>>(adj, adj16, NELT / 4);

  dim3 wg(16, 16);
  wconv2h<<<wg, 256, 0, stream>>>(Wenc, We_h, We_l, 1.0f);
  wconv1<<<wg, 256, 0, stream>>>(Wz, Wz1, 16.0f);
  wconv1<<<wg, 256, 0, stream>>>(Uz, Uz1, 16.0f);
  wconv2h<<<wg, 256, 0, stream>>>(Wr, Wr_h, Wr_l, 16.0f);
  wconv1<<<wg, 256, 0, stream>>>(Ur, Ur1, 16.0f);
  wconv2h<<<wg, 256, 0, stream>>>(Wh, Wh_h, Wh_l, 16.0f);
  wconv2h<<<wg, 256, 0, stream>>>(Uh, Uh_h, Uh_l, 4096.0f);

  const long NN = (long)LD * LD;

  // ENC (x3): h0 = mask*relu(x@Wenc+benc), chunked
  for (int ch = 0; ch < 2; ++ch) {
    Desc d{};
    d.A[0] = x_hi; d.B[0] = We_h;
    d.A[1] = x_lo; d.B[1] = We_h;
    d.A[2] = x_hi; d.B[2] = We_l;
    d.rowOff = ch * 16384;
    d.bias1 = benc; d.mask = mask; d.outf = hf; d.o16 = h16;
    gemm9<0, 3><<<256, 512, 0, stream>>>(d);
  }

  for (int s = 0; s < 2; ++s) {
    transp16<<<dim3(8, 8, 64), 256, 0, stream>>>(h16, zht);
    for (int ch = 0; ch < 2; ++ch) {  // chunk-major: whole step on half-M
      {  // A (x1, batched): a*2^-4 = (adj@h+ba)*2^-4, split store
        Desc d{};
        d.A[0] = adj16; d.B[0] = zht; d.bsA = NN; d.bsB = NN;
        d.bzOff = ch * 32;
        d.bias1 = ba_; d.o16 = a_hi; d.o16b = a_lo;
        gemm9<1, 1><<<256, 512, 0, stream>>>(d);
      }
      {  // Z (x2): z = relu(a@Wz + h@Uz + bz)
        Desc d{};
        d.A[0] = a_hi; d.B[0] = Wz1;
        d.A[1] = h16;  d.B[1] = Uz1;
        d.rowOff = ch * 16384;
        d.bias1 = bz_; d.o16 = zht;
        gemm9<2, 2><<<256, 512, 0, stream>>>(d);
      }
      {  // R (x4): rh = relu(a@Wr + h@Ur + br)*h, split store
        Desc d{};
        d.A[0] = a_hi; d.B[0] = Wr_h;
        d.A[1] = a_hi; d.B[1] = Wr_l;
        d.A[2] = a_lo; d.B[2] = Wr_h;
        d.A[3] = h16;  d.B[3] = Ur1;
        d.rowOff = ch * 16384;
        d.bias1 = br_; d.hf32 = hf; d.o16 = rh_hi; d.o16b = rh_lo;
        gemm9<3, 4><<<256, 512, 0, stream>>>(d);
      }
      if (s == 0) {  // GRU step 1 (x6): full split
        Desc d{};
        d.A[0] = a_hi;  d.B[0] = Wh_h;
        d.A[1] = a_hi;  d.B[1] = Wh_l;
        d.A[2] = a_lo;  d.B[2] = Wh_h;
        d.A[3] = rh_hi; d.B[3] = Uh_h;
        d.A[4] = rh_hi; d.B[4] = Uh_l;
        d.A[5] = rh_lo; d.B[5] = Uh_h;
        d.rowOff = ch * 16384;
        d.bias1 = bh_; d.mask = mask; d.hf32 = hf; d.z16 = zht;
        d.outf = hf; d.o16 = h16;
        gemm9<4, 6><<<256, 512, 0, stream>>>(d);
      } else {       // GRU step 2 (x2): inherited error dominates
        Desc d{};
        d.A[0] = a_hi;  d.B[0] = Wh_h;
        d.A[1] = rh_hi; d.B[1] = Uh_h;
        d.rowOff = ch * 16384;
        d.bias1 = bh_; d.mask = mask; d.hf32 = hf; d.z16 = zht;
        d.outf = hf; d.o16 = h16;
        gemm9<4, 2><<<256, 512, 0, stream>>>(d);
      }
    }
  }
}

// Round 10
// 765.131 us; speedup vs baseline: 1.0083x; 1.0083x over previous
//
#include <hip/hip_runtime.h>

// GGNN layer, B=64, N=512, D=512, steps=2. Numerics = rounds 6-9 product set
// (fp16 + power-of-2 scaling, split passes on r/hc path).
// r10: staged-byte attack. Empirical law across r2-r9: time = LDS-staged bytes
// / ~7.5 TB/s. Cuts: BM=256 (halves weight-panel duplication), pair-ordered
// operand reuse (skip re-staging shared A/B tiles), m97-proven sync structure
// (one full-drain syncthreads per pair), 512thr/8waves/acc64/2 blocks per CU.

#define LD 512
#define NN ((long)LD * LD)

typedef unsigned short u16;
typedef _Float16 f16;
typedef f16 f16x8 __attribute__((ext_vector_type(8)));
typedef float f32x4 __attribute__((ext_vector_type(4)));

__device__ __forceinline__ u16 f2h(float f) { f16 h = (f16)f; return *(u16*)&h; }
__device__ __forceinline__ float h2f(u16 b) { f16 h = *(f16*)&b; return (float)h; }

__device__ __forceinline__ void gload16(const void* g, void* l) {
  __builtin_amdgcn_global_load_lds(
      (const __attribute__((address_space(1))) void*)g,
      (__attribute__((address_space(3))) void*)l, 16, 0, 0);
}

// ---------------- f32 -> f16 single ----------------
__global__ void cvt_f16(const float* __restrict__ in, u16* __restrict__ out, int n4) {
  int i = blockIdx.x * blockDim.x + threadIdx.x;
  if (i >= n4) return;
  float4 v = reinterpret_cast<const float4*>(in)[i];
  ushort4 o;
  o.x = f2h(v.x); o.y = f2h(v.y); o.z = f2h(v.z); o.w = f2h(v.w);
  reinterpret_cast<ushort4*>(out)[i] = o;
}

// ---------------- f32 -> f16 hi/lo split ----------------
__global__ void cvt2h(const float* __restrict__ in, u16* __restrict__ ohi,
                      u16* __restrict__ olo, int n4) {
  int i = blockIdx.x * blockDim.x + threadIdx.x;
  if (i >= n4) return;
  float4 v = reinterpret_cast<const float4*>(in)[i];
  ushort4 h, l;
  h.x = f2h(v.x); l.x = f2h(v.x - h2f(h.x));
  h.y = f2h(v.y); l.y = f2h(v.y - h2f(h.y));
  h.z = f2h(v.z); l.z = f2h(v.z - h2f(h.z));
  h.w = f2h(v.w); l.w = f2h(v.w - h2f(h.w));
  reinterpret_cast<ushort4*>(ohi)[i] = h;
  reinterpret_cast<ushort4*>(olo)[i] = l;
}

// ------- weight f32 [K][N] -> f16 single (scaled), transposed [N][K] -------
__global__ void wconv1(const float* __restrict__ in, u16* __restrict__ out, float scale) {
  __shared__ float sm[32][33];
  int tx = threadIdx.x & 31, ty = threadIdx.x >> 5;
  int k0 = blockIdx.y * 32, n0 = blockIdx.x * 32;
#pragma unroll
  for (int i = 0; i < 32; i += 8)
    sm[ty + i][tx] = in[(size_t)(k0 + ty + i) * LD + n0 + tx];
  __syncthreads();
#pragma unroll
  for (int i = 0; i < 32; i += 8)
    out[(size_t)(n0 + ty + i) * LD + k0 + tx] = f2h(sm[tx][ty + i] * scale);
}

// ------- weight f32 [K][N] -> f16 hi/lo (scaled), transposed [N][K] -------
__global__ void wconv2h(const float* __restrict__ in, u16* __restrict__ ohi,
                        u16* __restrict__ olo, float scale) {
  __shared__ float sm[32][33];
  int tx = threadIdx.x & 31, ty = threadIdx.x >> 5;
  int k0 = blockIdx.y * 32, n0 = blockIdx.x * 32;
#pragma unroll
  for (int i = 0; i < 32; i += 8)
    sm[ty + i][tx] = in[(size_t)(k0 + ty + i) * LD + n0 + tx];
  __syncthreads();
#pragma unroll
  for (int i = 0; i < 32; i += 8) {
    float v = sm[tx][ty + i] * scale;
    u16 hi = f2h(v);
    size_t o = (size_t)(n0 + ty + i) * LD + k0 + tx;
    ohi[o] = hi;
    olo[o] = f2h(v - h2f(hi));
  }
}

// -------- u16 transpose per batch: [B][N][D] -> [B][D][N] --------
__global__ void transp16(const u16* __restrict__ in, u16* __restrict__ out) {
  __shared__ u16 sm[64][65];
  int b = blockIdx.z;
  int n0 = blockIdx.y * 64, d0 = blockIdx.x * 64;
  int lane = threadIdx.x & 63, grp = threadIdx.x >> 6;
  const u16* src = in + ((size_t)b * LD + n0) * LD + d0;
#pragma unroll
  for (int i = grp; i < 64; i += 4)
    sm[i][lane] = src[(size_t)i * LD + lane];
  __syncthreads();
  u16* dst = out + ((size_t)b * LD + d0) * LD + n0;
#pragma unroll
  for (int i = grp; i < 64; i += 4)
    dst[(size_t)i * LD + lane] = sm[lane][i];
}

// -------- pair plans (compile-time): ordered so adjacent pairs share a tile --------
struct PENC {  // (x_lo,Weh),(x_hi,Weh),(x_hi,Wel)
  static constexpr int P = 3;
  static constexpr int AI[3] = {0, 1, 1}, BI[3] = {0, 0, 1};
  static constexpr int SA[3] = {1, 1, 0}, SB[3] = {1, 0, 1};
};
struct PA {    // (adj,ht)
  static constexpr int P = 1;
  static constexpr int AI[1] = {0}, BI[1] = {0};
  static constexpr int SA[1] = {1}, SB[1] = {1};
};
struct PZ {    // (a_hi,Wz),(h16,Uz)
  static constexpr int P = 2;
  static constexpr int AI[2] = {0, 1}, BI[2] = {0, 1};
  static constexpr int SA[2] = {1, 1}, SB[2] = {1, 1};
};
struct PR {    // (a_hi,Wr_l),(a_hi,Wr_h),(a_lo,Wr_h),(h16,Ur)
  static constexpr int P = 4;
  static constexpr int AI[4] = {0, 0, 1, 2}, BI[4] = {0, 1, 1, 2};
  static constexpr int SA[4] = {1, 0, 1, 1}, SB[4] = {1, 1, 0, 1};
};
struct PG1 {   // (a_hi,Wh_l),(a_hi,Wh_h),(a_lo,Wh_h),(rh_lo,Uh_h),(rh_hi,Uh_h),(rh_hi,Uh_l)
  static constexpr int P = 6;
  static constexpr int AI[6] = {0, 0, 1, 2, 3, 3}, BI[6] = {0, 1, 1, 2, 2, 3};
  static constexpr int SA[6] = {1, 0, 1, 1, 1, 0}, SB[6] = {1, 1, 0, 1, 0, 1};
};
struct PG2 {   // (a_hi,Wh_h),(rh_hi,Uh_h)
  static constexpr int P = 2;
  static constexpr int AI[2] = {0, 1}, BI[2] = {0, 1};
  static constexpr int SA[2] = {1, 1}, SB[2] = {1, 1};
};

// ---------------- fused-pair fp16 MFMA GEMM, BM=256 BN=128 BK=32 ----------------
// EPI 0 ENC: v=relu(acc+b1)*mask[row]   -> outf, o16=v*2^-4
// EPI 1 A  : v=acc+b1*2^-4 (batched)    -> o16=hi(v), o16b=lo(v)
// EPI 2 Z  : v=relu(acc+b1)             -> o16=v*2^-4
// EPI 3 R  : v=relu(acc+b1)*hf32[idx]   -> o16=hi(v*2^-12), o16b=lo
// EPI 4 GRU: hc=tanh(acc+b1)*mask; z=16*z16; hn=(1-z)*hf32+z*hc -> outf, o16
struct Desc {
  const u16* Aop[4];
  const u16* Bop[4];
  const float* bias1;
  const float* mask;
  const float* hf32;
  const u16* z16;
  float* outf;
  u16* o16;
  u16* o16b;
};

template <int EPI, class PL>
__global__ __launch_bounds__(512, 4) void gemmf(Desc d) {
  __shared__ __align__(16) u16 As[2][8192];  // 256 x 32
  __shared__ __align__(16) u16 Bs[2][4096];  // 128 x 32

  const int t = threadIdx.x;
  const int lane = t & 63;
  const int wid = t >> 6;
  const int wr = wid >> 1, wc = wid & 1;  // 4x2 waves, 64x64 C each

  // XCD swizzle (512 blocks, 64/XCD): row-stripe -> XCD invariant across
  // all dispatches (producer/consumer L2 affinity).
  const int id = (int)blockIdx.x;
  const int swz = (id & 7) * 64 + (id >> 3);
  const int colb = swz & 3;
  const int rowb = swz >> 2;  // 0..127
  size_t baseA, baseB;
  int rowBase0;
  if (EPI == 1) {
    const int by2 = rowb & 1;
    const size_t bz = (size_t)(rowb >> 1);
    baseA = bz * NN + (size_t)by2 * 256 * LD;
    baseB = bz * NN + (size_t)colb * 128 * LD;
    rowBase0 = (int)bz * 512 + by2 * 256;
  } else {
    baseA = (size_t)rowb * 256 * LD;
    baseB = (size_t)colb * 128 * LD;
    rowBase0 = rowb * 256;
  }

  // stage: LDS dest linear (base + t*16B, rule 21); source col XOR-swizzled
  auto stageA = [&](const u16* Aop, int kb, u16* dst) {
#pragma unroll
    for (int s = 0; s < 2; ++s) {
      const int r = s * 128 + (t >> 2), c = t & 3;
      const int g = c ^ (r & 3) ^ ((r >> 2) & 3);
      gload16(Aop + baseA + (size_t)r * LD + kb + g * 8, dst + s * 4096 + t * 8);
    }
  };
  auto stageB = [&](const u16* Bop, int kb, u16* dst) {
    const int r = t >> 2, c = t & 3;
    const int g = c ^ (r & 3) ^ ((r >> 2) & 3);
    gload16(Bop + baseB + (size_t)r * LD + kb + g * 8, dst + t * 8);
  };

  // ds-read offsets (u16): row r has 4 swizzled 16B chunks; m(r)=(r&3)^((r>>2)&3)
  // is invariant across +16-row frag steps.
  const int lk = lane >> 4;
  const int RA = wr * 64 + (lane & 15);
  const int RB = wc * 64 + (lane & 15);
  const int offA = RA * 32 + ((lk ^ ((RA & 3) ^ ((RA >> 2) & 3))) * 8);
  const int offB = RB * 32 + ((lk ^ ((RB & 3) ^ ((RB >> 2) & 3))) * 8);

  f32x4 acc[4][4] = {};

  // prologue: stage pair 0 of kk 0
  stageA(d.Aop[PL::AI[0]], 0, As[0]);
  stageB(d.Bop[PL::BI[0]], 0, Bs[0]);
  asm volatile("s_waitcnt vmcnt(0)" ::: "memory");
  __builtin_amdgcn_s_barrier();

  int aS = 0, bS = 0;
  for (int kk = 0; kk < 16; ++kk) {
#pragma unroll
    for (int p = 0; p < PL::P; ++p) {
      f16x8 af[4], bf[4];
#pragma unroll
      for (int i = 0; i < 4; ++i) af[i] = *(const f16x8*)&As[aS][offA + i * 512];
#pragma unroll
      for (int j = 0; j < 4; ++j) bf[j] = *(const f16x8*)&Bs[bS][offB + j * 512];
      // stage next pair (overlaps the MFMA below; drained by syncthreads)
      const int np = (p + 1 == PL::P) ? 0 : p + 1;
      const int nkb = (p + 1 == PL::P) ? (kk + 1) * 32 : kk * 32;
      const bool last = (kk == 15) && (p == PL::P - 1);
      if (!last) {
        if (PL::SA[np]) stageA(d.Aop[PL::AI[np]], nkb, As[aS ^ 1]);
        if (PL::SB[np]) stageB(d.Bop[PL::BI[np]], nkb, Bs[bS ^ 1]);
      }
      __builtin_amdgcn_s_setprio(1);
#pragma unroll
      for (int i = 0; i < 4; ++i)
#pragma unroll
        for (int j = 0; j < 4; ++j)
          acc[i][j] = __builtin_amdgcn_mfma_f32_16x16x32_f16(af[i], bf[j], acc[i][j], 0, 0, 0);
      __builtin_amdgcn_s_setprio(0);
      __syncthreads();  // vmcnt(0)+lgkmcnt(0)+barrier: stages landed, reads done
      if (!last) {
        aS ^= PL::SA[np];
        bS ^= PL::SB[np];
      }
    }
  }

  // epilogue: C/D layout col=lane&15, row=(lane>>4)*4+reg [m89-verified]
  const float S4 = 0.0625f;          // 2^-4
  const float S12 = 2.44140625e-4f;  // 2^-12
  const int rowBase = rowBase0 + wr * 64 + (lane >> 4) * 4;
  const int colBase = colb * 128 + wc * 64 + (lane & 15);
#pragma unroll
  for (int i = 0; i < 4; ++i) {
#pragma unroll
    for (int j = 0; j < 4; ++j) {
      const int col = colBase + j * 16;
      const float bv = d.bias1[col];
#pragma unroll
      for (int r = 0; r < 4; ++r) {
        const int row = rowBase + i * 16 + r;
        const size_t idx = (size_t)row * LD + col;
        const float a = acc[i][j][r];
        if (EPI == 0) {
          float v = fmaxf(a + bv, 0.0f) * d.mask[row];
          d.outf[idx] = v;
          d.o16[idx] = f2h(v * S4);
        } else if (EPI == 1) {
          float v = a + bv * S4;
          u16 hi = f2h(v);
          d.o16[idx] = hi;
          d.o16b[idx] = f2h(v - h2f(hi));
        } else if (EPI == 2) {
          float v = fmaxf(a + bv, 0.0f);
          d.o16[idx] = f2h(v * S4);
        } else if (EPI == 3) {
          float v = fmaxf(a + bv, 0.0f) * d.hf32[idx];
          u16 hi = f2h(v * S12);
          d.o16[idx] = hi;
          float rec = h2f(hi) * 4096.0f;
          d.o16b[idx] = f2h((v - rec) * S12);
        } else {
          float hc = tanhf(a + bv) * d.mask[row];
          float z = 16.0f * h2f(d.z16[idx]);
          float h = d.hf32[idx];
          float hn = (1.0f - z) * h + z * hc;
          d.outf[idx] = hn;
          d.o16[idx] = f2h(hn * S4);
        }
      }
    }
  }
}

extern "C" void kernel_launch(void* const* d_in, const int* in_sizes, int n_in,
                              void* d_out, int out_size, void* d_ws, size_t ws_size,
                              hipStream_t stream) {
  const float* x    = (const float*)d_in[0];
  const float* adj  = (const float*)d_in[1];
  const float* mask = (const float*)d_in[2];
  const float* Wenc = (const float*)d_in[3];
  const float* benc = (const float*)d_in[4];
  const float* Wz   = (const float*)d_in[5];
  const float* Uz   = (const float*)d_in[6];
  const float* bz_  = (const float*)d_in[7];
  const float* Wr   = (const float*)d_in[8];
  const float* Ur   = (const float*)d_in[9];
  const float* br_  = (const float*)d_in[10];
  const float* Wh   = (const float*)d_in[11];
  const float* Uh   = (const float*)d_in[12];
  const float* bh_  = (const float*)d_in[13];
  const float* ba_  = (const float*)d_in[14];

  float* hf = (float*)d_out;  // h in f32 across steps (64 MiB)

  const size_t SZ  = (size_t)64 * 512 * 512 * sizeof(u16);  // 32 MiB
  const size_t WSZ = (size_t)LD * LD * sizeof(u16);         // 0.5 MiB
  const size_t NEED = 7 * SZ + 11 * WSZ;                    // 229.5 MiB
  if (ws_size < NEED) return;

  char* p = (char*)d_ws;
  u16* adj16 = (u16*)p; p += SZ;
  u16* h16   = (u16*)p; p += SZ;   // h * 2^-4
  u16* a_hi  = (u16*)p; p += SZ;   // a*2^-4 hi ; aliased: x_hi before encoder
  u16* a_lo  = (u16*)p; p += SZ;   // a*2^-4 lo ; aliased: x_lo before encoder
  u16* zht   = (u16*)p; p += SZ;   // h^T*2^-4 (transp..A), then z*2^-4 (Z..GRU)
  u16* rh_hi = (u16*)p; p += SZ;   // rh*2^-12 hi
  u16* rh_lo = (u16*)p; p += SZ;   // rh*2^-12 lo
  u16* w     = (u16*)p;
  u16* We_h = w + 0 * LD * LD;  u16* We_l = w + 1 * LD * LD;   // x1
  u16* Wz1  = w + 2 * LD * LD;                                  // x16
  u16* Uz1  = w + 3 * LD * LD;                                  // x16
  u16* Wr_h = w + 4 * LD * LD;  u16* Wr_l = w + 5 * LD * LD;   // x16
  u16* Ur1  = w + 6 * LD * LD;                                  // x16
  u16* Wh_h = w + 7 * LD * LD;  u16* Wh_l = w + 8 * LD * LD;   // x16
  u16* Uh_h = w + 9 * LD * LD;  u16* Uh_l = w + 10 * LD * LD;  // x4096
  u16* x_hi = a_hi;
  u16* x_lo = a_lo;

  const int NELT = 64 * 512 * 512;
  cvt2h<<<NELT / 4 / 256, 256, 0, stream>>>(x, x_hi, x_lo, NELT / 4);
  cvt_f16<<<NELT / 4 / 256, 256, 0, stream>>>(adj, adj16, NELT / 4);

  dim3 wg(16, 16);
  wconv2h<<<wg, 256, 0, stream>>>(Wenc, We_h, We_l, 1.0f);
  wconv1<<<wg, 256, 0, stream>>>(Wz, Wz1, 16.0f);
  wconv1<<<wg, 256, 0, stream>>>(Uz, Uz1, 16.0f);
  wconv2h<<<wg, 256, 0, stream>>>(Wr, Wr_h, Wr_l, 16.0f);
  wconv1<<<wg, 256, 0, stream>>>(Ur, Ur1, 16.0f);
  wconv2h<<<wg, 256, 0, stream>>>(Wh, Wh_h, Wh_l, 16.0f);
  wconv2h<<<wg, 256, 0, stream>>>(Uh, Uh_h, Uh_l, 4096.0f);

  // ENC: h0 = mask*relu(x@Wenc+benc)
  {
    Desc d{};
    d.Aop[0] = x_lo; d.Aop[1] = x_hi;
    d.Bop[0] = We_h; d.Bop[1] = We_l;
    d.bias1 = benc; d.mask = mask; d.outf = hf; d.o16 = h16;
    gemmf<0, PENC><<<512, 512, 0, stream>>>(d);
  }

  for (int s = 0; s < 2; ++s) {
    transp16<<<dim3(8, 8, 64), 256, 0, stream>>>(h16, zht);
    {  // A (batched): a*2^-4 = (adj@h+ba)*2^-4, split store
      Desc d{};
      d.Aop[0] = adj16; d.Bop[0] = zht;
      d.bias1 = ba_; d.o16 = a_hi; d.o16b = a_lo;
      gemmf<1, PA><<<512, 512, 0, stream>>>(d);
    }
    {  // Z: z = relu(a@Wz + h@Uz + bz)
      Desc d{};
      d.Aop[0] = a_hi; d.Aop[1] = h16;
      d.Bop[0] = Wz1;  d.Bop[1] = Uz1;
      d.bias1 = bz_; d.o16 = zht;
      gemmf<2, PZ><<<512, 512, 0, stream>>>(d);
    }
    {  // R: rh = relu(a@Wr + h@Ur + br)*h, split store
      Desc d{};
      d.Aop[0] = a_hi; d.Aop[1] = a_lo; d.Aop[2] = h16;
      d.Bop[0] = Wr_l; d.Bop[1] = Wr_h; d.Bop[2] = Ur1;
      d.bias1 = br_; d.hf32 = hf; d.o16 = rh_hi; d.o16b = rh_lo;
      gemmf<3, PR><<<512, 512, 0, stream>>>(d);
    }
    if (s == 0) {  // GRU step 1: full split
      Desc d{};
      d.Aop[0] = a_hi; d.Aop[1] = a_lo; d.Aop[2] = rh_lo; d.Aop[3] = rh_hi;
      d.Bop[0] = Wh_l; d.Bop[1] = Wh_h; d.Bop[2] = Uh_h;  d.Bop[3] = Uh_l;
      d.bias1 = bh_; d.mask = mask; d.hf32 = hf; d.z16 = zht;
      d.outf = hf; d.o16 = h16;
      gemmf<4, PG1><<<512, 512, 0, stream>>>(d);
    } else {       // GRU step 2: inherited error dominates
      Desc d{};
      d.Aop[0] = a_hi; d.Aop[1] = rh_hi;
      d.Bop[0] = Wh_h; d.Bop[1] = Uh_h;
      d.bias1 = bh_; d.mask = mask; d.hf32 = hf; d.z16 = zht;
      d.outf = hf; d.o16 = h16;
      gemmf<4, PG2><<<512, 512, 0, stream>>>(d);
    }
  }
}